// Round 4
// baseline (1767.961 us; speedup 1.0000x reference)
//
#include <hip/hip_runtime.h>
#include <math.h>

#define N_USERS 100000
#define N_ITEMS 50000
#define NE      2000000
#define NB      100000
#define H       64
#define BN_EPS  1e-5f
#define NXCD    8
#define U_LOC   (N_USERS / NXCD)          // 12500 users per partition
#define I_LOC   (N_ITEMS / NXCD)          // 6250 items per partition
#define HSLOTS  (U_LOC + I_LOC)           // 18750 ints = 75 KB LDS
#define S_SLICES 64                        // edge slices per partition
#define NBLK_CSR (NXCD * S_SLICES)         // 512 blocks
#define E_SLICE  (NE / S_SLICES)           // 31250 edges per slice

static __device__ __forceinline__ int rfl(int x) { return __builtin_amdgcn_readfirstlane(x); }

// ---------------- projection: Y[N,64] = X[N,K] @ W[K,64] + b ----------------
// 4 waves split K (slice in VGPRs, lane = out channel). 8 rows per block
// iteration: 8 independent accumulator chains/wave (hides 4-cy FMA latency),
// 8 rows of wave-uniform scalar X loads in flight, one barrier per 8 rows.
// Requires nrows % 8 == 0 (100000, 50000 both OK).
template<int K>
__global__ __launch_bounds__(256) void proj_kernel(
    const float* __restrict__ X, const float* __restrict__ W,
    const float* __restrict__ bias, float* __restrict__ Y, int nrows) {
  constexpr int SL = K / 4;
  constexpr int RB = 8;
  const int lane = threadIdx.x & 63;
  const int wid  = rfl((int)(threadIdx.x >> 6));
  const int k0   = wid * SL;
  float w[SL];
#pragma unroll
  for (int k = 0; k < SL; k++) w[k] = W[(k0 + k) * H + lane];
  const float bv = bias[lane];
  __shared__ float part[4][RB][64];
  for (int rb = blockIdx.x * RB; rb < nrows; rb += gridDim.x * RB) {
    const float* xp = X + (size_t)rb * K + k0;
    float acc[RB];
#pragma unroll
    for (int j = 0; j < RB; j++) acc[j] = 0.f;
#pragma unroll 4
    for (int k = 0; k < SL; k++) {
#pragma unroll
      for (int j = 0; j < RB; j++)
        acc[j] = fmaf(xp[(size_t)j * K + k], w[k], acc[j]);
    }
#pragma unroll
    for (int j = 0; j < RB; j++) part[wid][j][lane] = acc[j];
    __syncthreads();
#pragma unroll
    for (int j = 0; j < 2; j++) {
      const int row = wid * 2 + j;
      Y[(size_t)(rb + row) * H + lane] =
          part[0][row][lane] + part[1][row][lane] +
          part[2][row][lane] + part[3][row][lane] + bv;
    }
    __syncthreads();
  }
}

// ---------------- CSR build, atomic-free counting sort ----------------
__global__ __launch_bounds__(256) void hist2_kernel(
    const int* __restrict__ src, const int* __restrict__ dst,
    int* __restrict__ PH) {
  __shared__ int h[HSLOTS];
  const int x = blockIdx.x & (NXCD - 1);
  const int s = blockIdx.x >> 3;
  for (int i = threadIdx.x; i < HSLOTS; i += 256) h[i] = 0;
  __syncthreads();
  const int uLo = x * U_LOC, iLo = x * I_LOC;
  const int e0 = s * E_SLICE;
  for (int e = e0 + threadIdx.x; e < e0 + E_SLICE; e += 256) {
    const int u  = __builtin_nontemporal_load(&src[e]);
    const int it = __builtin_nontemporal_load(&dst[e]);
    const int ul = u - uLo, il = it - iLo;
    if ((unsigned)ul < (unsigned)U_LOC) atomicAdd(&h[ul], 1);
    if ((unsigned)il < (unsigned)I_LOC) atomicAdd(&h[U_LOC + il], 1);
  }
  __syncthreads();
  int* out = PH + (size_t)blockIdx.x * HSLOTS;
  for (int i = threadIdx.x; i < HSLOTS; i += 256) out[i] = h[i];
}

__global__ __launch_bounds__(256) void combine_kernel(
    int* __restrict__ PH, int* __restrict__ cntU, int* __restrict__ cntI) {
  const int g = blockIdx.x * 256 + threadIdx.x;
  if (g >= NXCD * HSLOTS) return;
  const int x = g / HSLOTS;
  const int n = g - x * HSLOTS;
  int* p = PH + (size_t)x * HSLOTS + n;
  int run = 0;
#pragma unroll 4
  for (int s = 0; s < S_SLICES; s++) {
    int* q = p + (size_t)s * (NXCD * HSLOTS);
    const int v = *q;
    *q = run;
    run += v;
  }
  if (n < U_LOC) cntU[x * U_LOC + n] = run;
  else           cntI[x * I_LOC + (n - U_LOC)] = run;
}

// single-block exclusive scan: 8 elems/thread, wave shfl-scan + LDS combine
__global__ __launch_bounds__(1024) void scan_kernel(
    const int* __restrict__ cnt, int* __restrict__ row, int n) {
  __shared__ int wtot[16];
  __shared__ int carry_s;
  const int tid = threadIdx.x;
  const int lane = tid & 63, wv = tid >> 6;
  if (tid == 0) { carry_s = 0; row[0] = 0; }
  __syncthreads();
  for (int base = 0; base < n; base += 8192) {
    const int i0 = base + tid * 8;
    int v, sacc[8];
    int run = 0;
#pragma unroll
    for (int k = 0; k < 8; k++) {
      v = (i0 + k < n) ? cnt[i0 + k] : 0;
      run += v;
      sacc[k] = run;
    }
    int x = run;
#pragma unroll
    for (int off = 1; off < 64; off <<= 1) {
      const int y = __shfl_up(x, off);
      if (lane >= off) x += y;
    }
    if (lane == 63) wtot[wv] = x;
    __syncthreads();
    int woff = 0;
#pragma unroll
    for (int k = 0; k < 16; k++) woff += (k < wv) ? wtot[k] : 0;
    const int thr_excl = (x - run) + woff + carry_s;
#pragma unroll
    for (int k = 0; k < 8; k++)
      if (i0 + k < n) row[i0 + k + 1] = thr_excl + sacc[k];
    __syncthreads();
    if (tid == 1023) carry_s = thr_excl + run;
    __syncthreads();
  }
}

__global__ __launch_bounds__(256) void scatter2_kernel(
    const int* __restrict__ src, const int* __restrict__ dst,
    const int* __restrict__ PH, const int* __restrict__ rowU,
    const int* __restrict__ rowI, int* __restrict__ adjU,
    int* __restrict__ adjI) {
  __shared__ int pos[HSLOTS];
  const int x = blockIdx.x & (NXCD - 1);
  const int s = blockIdx.x >> 3;
  const int uLo = x * U_LOC, iLo = x * I_LOC;
  const int* pre = PH + (size_t)blockIdx.x * HSLOTS;
  for (int i = threadIdx.x; i < U_LOC; i += 256)
    pos[i] = rowU[uLo + i] + pre[i];
  for (int i = threadIdx.x; i < I_LOC; i += 256)
    pos[U_LOC + i] = rowI[iLo + i] + pre[U_LOC + i];
  __syncthreads();
  const int e0 = s * E_SLICE;
  for (int e = e0 + threadIdx.x; e < e0 + E_SLICE; e += 256) {
    const int u  = __builtin_nontemporal_load(&src[e]);
    const int it = __builtin_nontemporal_load(&dst[e]);
    const int ul = u - uLo, il = it - iLo;
    if ((unsigned)ul < (unsigned)U_LOC) {
      const int p = atomicAdd(&pos[ul], 1);
      adjU[p] = it;
    }
    if ((unsigned)il < (unsigned)I_LOC) {
      const int p = atomicAdd(&pos[U_LOC + il], 1);
      adjI[p] = u;
    }
  }
}

// ---------------- aggregations: one wave per segment, lane = channel ----------------
__global__ __launch_bounds__(256) void agg_max_kernel(
    const float* __restrict__ feat, const int* __restrict__ rowptr,
    const int* __restrict__ adj, float* __restrict__ out, int nseg) {
  const int lane = threadIdx.x & 63;
  const int wid  = rfl((int)(threadIdx.x >> 6));
  for (int s = blockIdx.x * 4 + wid; s < nseg; s += gridDim.x * 4) {
    const int beg = rowptr[s], end = rowptr[s + 1];
    float m0 = -INFINITY, m1 = -INFINITY, m2 = -INFINITY, m3 = -INFINITY;
    int j = beg;
    for (; j + 4 <= end; j += 4) {
      const int n0 = adj[j], n1 = adj[j + 1], n2 = adj[j + 2], n3 = adj[j + 3];
      m0 = fmaxf(m0, feat[(size_t)n0 * H + lane]);
      m1 = fmaxf(m1, feat[(size_t)n1 * H + lane]);
      m2 = fmaxf(m2, feat[(size_t)n2 * H + lane]);
      m3 = fmaxf(m3, feat[(size_t)n3 * H + lane]);
    }
    for (; j < end; j++) m0 = fmaxf(m0, feat[(size_t)adj[j] * H + lane]);
    const float m = fmaxf(fmaxf(m0, m1), fmaxf(m2, m3));
    out[(size_t)s * H + lane] = (end > beg) ? m : 0.f;  // empty segment -> 0 (PyG)
  }
}

__global__ __launch_bounds__(256) void agg_mean_kernel(
    const float* __restrict__ feat, const int* __restrict__ rowptr,
    const int* __restrict__ adj, float* __restrict__ out, int nseg) {
  const int lane = threadIdx.x & 63;
  const int wid  = rfl((int)(threadIdx.x >> 6));
  for (int s = blockIdx.x * 4 + wid; s < nseg; s += gridDim.x * 4) {
    const int beg = rowptr[s], end = rowptr[s + 1];
    float a0 = 0.f, a1 = 0.f, a2 = 0.f, a3 = 0.f;
    int j = beg;
    for (; j + 4 <= end; j += 4) {
      const int n0 = adj[j], n1 = adj[j + 1], n2 = adj[j + 2], n3 = adj[j + 3];
      a0 += feat[(size_t)n0 * H + lane];
      a1 += feat[(size_t)n1 * H + lane];
      a2 += feat[(size_t)n2 * H + lane];
      a3 += feat[(size_t)n3 * H + lane];
    }
    for (; j < end; j++) a0 += feat[(size_t)adj[j] * H + lane];
    const float inv = 1.f / (float)((end - beg) > 1 ? (end - beg) : 1);
    out[(size_t)s * H + lane] = ((a0 + a1) + (a2 + a3)) * inv;
  }
}

// ---------------- fused conv: Y = relu(BN(AGG@Wl + bl + XS@Wr)) ----------------
// One wave handles 4 rows fully (K=128 weights in VGPRs): 4 independent
// accumulator chains, no barriers. Requires nrows % 4 == 0.
__global__ __launch_bounds__(256) void conv_kernel(
    const float* __restrict__ AGG, const float* __restrict__ XS,
    const float* __restrict__ Wl, const float* __restrict__ bl,
    const float* __restrict__ Wr, const float* __restrict__ gm,
    const float* __restrict__ bt, const float* __restrict__ mu,
    const float* __restrict__ vr, float* __restrict__ Y, int nrows) {
  constexpr int RB = 4;
  const int lane = threadIdx.x & 63;
  const int wid  = rfl((int)(threadIdx.x >> 6));
  float wl[64], wr[64];
#pragma unroll
  for (int k = 0; k < 64; k++) wl[k] = Wl[k * 64 + lane];
#pragma unroll
  for (int k = 0; k < 64; k++) wr[k] = Wr[k * 64 + lane];
  const float s = gm[lane] * rsqrtf(vr[lane] + BN_EPS);
  const float C = (bl[lane] - mu[lane]) * s + bt[lane];
  for (int r0 = (blockIdx.x * 4 + wid) * RB; r0 < nrows; r0 += gridDim.x * 4 * RB) {
    const float* a = AGG + (size_t)r0 * 64;
    const float* x = XS + (size_t)r0 * 64;
    float acc[RB];
#pragma unroll
    for (int j = 0; j < RB; j++) acc[j] = 0.f;
#pragma unroll 4
    for (int k = 0; k < 64; k++) {
#pragma unroll
      for (int j = 0; j < RB; j++)
        acc[j] = fmaf(a[(size_t)j * 64 + k], wl[k], acc[j]);
    }
#pragma unroll 4
    for (int k = 0; k < 64; k++) {
#pragma unroll
      for (int j = 0; j < RB; j++)
        acc[j] = fmaf(x[(size_t)j * 64 + k], wr[k], acc[j]);
    }
#pragma unroll
    for (int j = 0; j < RB; j++)
      Y[(size_t)(r0 + j) * 64 + lane] = fmaxf(fmaf(acc[j], s, C), 0.f);
  }
}

// ---------------- head ----------------
__global__ __launch_bounds__(256) void head_kernel(
    const float* __restrict__ ux, const float* __restrict__ ix,
    const int* __restrict__ eliU, const int* __restrict__ eliI,
    const float* __restrict__ W1, const float* __restrict__ b1,
    const float* __restrict__ W2, const float* __restrict__ b2,
    float* __restrict__ out) {
  const int lane = threadIdx.x & 63;
  const int wid  = rfl((int)(threadIdx.x >> 6));
  float w1[128];
#pragma unroll
  for (int k = 0; k < 128; k++) w1[k] = W1[k * 64 + lane];
  const float b1v = b1[lane];
  const float w2a = W2[lane * 4 + 0], w2b = W2[lane * 4 + 1];
  const float w2c = W2[lane * 4 + 2], w2d = W2[lane * 4 + 3];
  const float c0 = b2[0], c1 = b2[1], c2 = b2[2], c3 = b2[3];
  for (int b = blockIdx.x * 4 + wid; b < NB; b += gridDim.x * 4) {
    const int u = eliU[b], it = eliI[b];
    const float* xu = ux + (size_t)u * 64;
    const float* xi = ix + (size_t)it * 64;
    float acc = b1v;
#pragma unroll
    for (int k = 0; k < 64; k++) acc = fmaf(xu[k], w1[k], acc);
#pragma unroll
    for (int k = 0; k < 64; k++) acc = fmaf(xi[k], w1[64 + k], acc);
    const float h = fmaxf(acc, 0.f);
    float o0 = h * w2a, o1 = h * w2b, o2 = h * w2c, o3 = h * w2d;
#pragma unroll
    for (int off = 32; off; off >>= 1) {
      o0 += __shfl_down(o0, off);
      o1 += __shfl_down(o1, off);
      o2 += __shfl_down(o2, off);
      o3 += __shfl_down(o3, off);
    }
    if (lane == 0) {
      float4 o = { o0 + c0, o1 + c1, o2 + c2, o3 + c3 };
      *reinterpret_cast<float4*>(out + (size_t)b * 4) = o;
    }
  }
}

// ---------------- launch ----------------
extern "C" void kernel_launch(void* const* d_in, const int* in_sizes, int n_in,
                              void* d_out, int out_size, void* d_ws, size_t ws_size,
                              hipStream_t stream) {
  const float* userF = (const float*)d_in[0];
  const float* itemF = (const float*)d_in[1];
  const int*   src   = (const int*)d_in[2];
  const int*   dst   = src + NE;
  const int*   eliU  = (const int*)d_in[3];
  const int*   eliI  = eliU + NB;
  const float* upW = (const float*)d_in[4],  *upb = (const float*)d_in[5];
  const float* ipW = (const float*)d_in[6],  *ipb = (const float*)d_in[7];
  const float* ulW = (const float*)d_in[8],  *ulb = (const float*)d_in[9];
  const float* urW = (const float*)d_in[10];
  const float* ilW = (const float*)d_in[11], *ilb = (const float*)d_in[12];
  const float* irW = (const float*)d_in[13];
  const float* ug  = (const float*)d_in[14], *ube = (const float*)d_in[15];
  const float* um  = (const float*)d_in[16], *uv  = (const float*)d_in[17];
  const float* ig  = (const float*)d_in[18], *ibe = (const float*)d_in[19];
  const float* im  = (const float*)d_in[20], *iv  = (const float*)d_in[21];
  const float* f1W = (const float*)d_in[22], *f1b = (const float*)d_in[23];
  const float* f2W = (const float*)d_in[24], *f2b = (const float*)d_in[25];
  float* outp = (float*)d_out;

  char* p = (char*)d_ws;
  auto alloc = [&](size_t bytes) {
    char* r = p;
    p += (bytes + 255) & ~(size_t)255;
    return r;
  };
  float* ux0  = (float*)alloc((size_t)N_USERS * H * 4);
  float* ux1  = (float*)alloc((size_t)N_USERS * H * 4);
  float* ix0  = (float*)alloc((size_t)N_ITEMS * H * 4);
  float* ix1  = (float*)alloc((size_t)N_ITEMS * H * 4);
  float* agU  = (float*)alloc((size_t)N_USERS * H * 4);   // 25.6 MB
  float* agI  = (float*)alloc((size_t)N_ITEMS * H * 4);   // 12.8 MB (contiguous after agU)
  int*   rowU = (int*)alloc((size_t)(N_USERS + 1) * 4);
  int*   rowI = (int*)alloc((size_t)(N_ITEMS + 1) * 4);
  int*   cntU = (int*)alloc((size_t)N_USERS * 4);
  int*   cntI = (int*)alloc((size_t)N_ITEMS * 4);
  int*   adjU = (int*)alloc((size_t)NE * 4);
  int*   adjI = (int*)alloc((size_t)NE * 4);
  // PH (512 x 18750 ints = 38.4 MB) aliases agU+agI (dead until agg phase).
  int*   PH   = (int*)agU;

  const int G = 2048, T = 256;
  proj_kernel<256><<<G, T, 0, stream>>>(userF, upW, upb, ux0, N_USERS);
  proj_kernel<128><<<G, T, 0, stream>>>(itemF, ipW, ipb, ix0, N_ITEMS);
  hist2_kernel<<<NBLK_CSR, T, 0, stream>>>(src, dst, PH);
  combine_kernel<<<(NXCD * HSLOTS + 255) / 256, T, 0, stream>>>(PH, cntU, cntI);
  scan_kernel<<<1, 1024, 0, stream>>>(cntU, rowU, N_USERS);
  scan_kernel<<<1, 1024, 0, stream>>>(cntI, rowI, N_ITEMS);
  scatter2_kernel<<<NBLK_CSR, T, 0, stream>>>(src, dst, PH, rowU, rowI, adjU, adjI);

  const float* uin = ux0;
  const float* iin = ix0;
  float* uout = ux1;
  float* iout = ix1;
  for (int l = 0; l < 2; l++) {
    agg_max_kernel<<<G, T, 0, stream>>>(iin, rowU, adjU, agU, N_USERS);
    conv_kernel<<<G, T, 0, stream>>>(agU, uin, ulW + l * 4096, ulb + l * 64,
                                     urW + l * 4096, ug + l * 64, ube + l * 64,
                                     um + l * 64, uv + l * 64, uout, N_USERS);
    agg_mean_kernel<<<G, T, 0, stream>>>(uin, rowI, adjI, agI, N_ITEMS);
    conv_kernel<<<G, T, 0, stream>>>(agI, iin, ilW + l * 4096, ilb + l * 64,
                                     irW + l * 4096, ig + l * 64, ibe + l * 64,
                                     im + l * 64, iv + l * 64, iout, N_ITEMS);
    const float* t;
    t = uin; uin = uout; uout = (float*)t;
    t = iin; iin = iout; iout = (float*)t;
  }
  head_kernel<<<G, T, 0, stream>>>(uin, iin, eliU, eliI, f1W, f1b, f2W, f2b, outp);
}

// Round 5
// 1000.983 us; speedup vs baseline: 1.7662x; 1.7662x over previous
//
#include <hip/hip_runtime.h>
#include <math.h>

#define N_USERS 100000
#define N_ITEMS 50000
#define NE      2000000
#define NB      100000
#define H       64
#define BN_EPS  1e-5f
#define NXCD    8
#define U_LOC   (N_USERS / NXCD)          // 12500 users per partition
#define I_LOC   (N_ITEMS / NXCD)          // 6250 items per partition
#define HSLOTS  (U_LOC + I_LOC)           // 18750 ints = 75 KB LDS
#define S_SLICES 64                        // edge slices per partition
#define NBLK_CSR (NXCD * S_SLICES)         // 512 blocks
#define E_SLICE  (NE / S_SLICES)           // 31250 edges per slice

static __device__ __forceinline__ int rfl(int x) { return __builtin_amdgcn_readfirstlane(x); }

// ---------------- projection: Y[N,64] = X[N,K] @ W[K,64] + b ----------------
// 4 waves split K (slice in VGPRs, lane = out channel). ONE sequential row
// stream per wave (R3 lesson: interleaved row streams thrash the uniform-load
// cache path -> 4.7x HBM overfetch). ILP from 4 split accumulators (k stride
// 4): chain 16x4cy < 64x2cy issue. 2 contiguous rows per iteration processed
// SEQUENTIALLY; double-buffered LDS reduce -> 1 barrier per 2 rows.
template<int K>
__global__ __launch_bounds__(256) void proj_kernel(
    const float* __restrict__ X, const float* __restrict__ W,
    const float* __restrict__ bias, float* __restrict__ Y, int nrows) {
  constexpr int SL = K / 4;
  const int lane = threadIdx.x & 63;
  const int wid  = rfl((int)(threadIdx.x >> 6));
  const int k0   = wid * SL;
  float w[SL];
#pragma unroll
  for (int k = 0; k < SL; k++) w[k] = W[(k0 + k) * H + lane];
  const float bv = bias[lane];
  __shared__ float part[2][4][2][64];   // [parity][wave][row][chan]
  int par = 0;
  for (int rb = blockIdx.x * 2; rb < nrows; rb += gridDim.x * 2, par ^= 1) {
#pragma unroll
    for (int row = 0; row < 2; row++) {
      const float* xr = X + (size_t)(rb + row) * K + k0;
      float a0 = 0.f, a1 = 0.f, a2 = 0.f, a3 = 0.f;
#pragma unroll
      for (int k = 0; k < SL; k += 4) {
        a0 = fmaf(xr[k + 0], w[k + 0], a0);
        a1 = fmaf(xr[k + 1], w[k + 1], a1);
        a2 = fmaf(xr[k + 2], w[k + 2], a2);
        a3 = fmaf(xr[k + 3], w[k + 3], a3);
      }
      part[par][wid][row][lane] = (a0 + a1) + (a2 + a3);
    }
    __syncthreads();
    if (wid < 2) {
      Y[(size_t)(rb + wid) * H + lane] =
          part[par][0][wid][lane] + part[par][1][wid][lane] +
          part[par][2][wid][lane] + part[par][3][wid][lane] + bv;
    }
    // no trailing barrier: next iter writes part[par^1]; part[par] is reread
    // only after the following barrier -> double buffer is race-free.
  }
}

// ---------------- CSR build, atomic-free counting sort ----------------
__global__ __launch_bounds__(256) void hist2_kernel(
    const int* __restrict__ src, const int* __restrict__ dst,
    int* __restrict__ PH) {
  __shared__ int h[HSLOTS];
  const int x = blockIdx.x & (NXCD - 1);
  const int s = blockIdx.x >> 3;
  for (int i = threadIdx.x; i < HSLOTS; i += 256) h[i] = 0;
  __syncthreads();
  const int uLo = x * U_LOC, iLo = x * I_LOC;
  const int e0 = s * E_SLICE;
  for (int e = e0 + threadIdx.x; e < e0 + E_SLICE; e += 256) {
    const int u  = __builtin_nontemporal_load(&src[e]);
    const int it = __builtin_nontemporal_load(&dst[e]);
    const int ul = u - uLo, il = it - iLo;
    if ((unsigned)ul < (unsigned)U_LOC) atomicAdd(&h[ul], 1);
    if ((unsigned)il < (unsigned)I_LOC) atomicAdd(&h[U_LOC + il], 1);
  }
  __syncthreads();
  int* out = PH + (size_t)blockIdx.x * HSLOTS;
  for (int i = threadIdx.x; i < HSLOTS; i += 256) out[i] = h[i];
}

__global__ __launch_bounds__(256) void combine_kernel(
    int* __restrict__ PH, int* __restrict__ cntU, int* __restrict__ cntI) {
  const int g = blockIdx.x * 256 + threadIdx.x;
  if (g >= NXCD * HSLOTS) return;
  const int x = g / HSLOTS;
  const int n = g - x * HSLOTS;
  int* p = PH + (size_t)x * HSLOTS + n;
  int run = 0;
#pragma unroll 4
  for (int s = 0; s < S_SLICES; s++) {
    int* q = p + (size_t)s * (NXCD * HSLOTS);
    const int v = *q;
    *q = run;
    run += v;
  }
  if (n < U_LOC) cntU[x * U_LOC + n] = run;
  else           cntI[x * I_LOC + (n - U_LOC)] = run;
}

// single-block exclusive scan: 8 elems/thread, wave shfl-scan + LDS combine
__global__ __launch_bounds__(1024) void scan_kernel(
    const int* __restrict__ cnt, int* __restrict__ row, int n) {
  __shared__ int wtot[16];
  __shared__ int carry_s;
  const int tid = threadIdx.x;
  const int lane = tid & 63, wv = tid >> 6;
  if (tid == 0) { carry_s = 0; row[0] = 0; }
  __syncthreads();
  for (int base = 0; base < n; base += 8192) {
    const int i0 = base + tid * 8;
    int v, sacc[8];
    int run = 0;
#pragma unroll
    for (int k = 0; k < 8; k++) {
      v = (i0 + k < n) ? cnt[i0 + k] : 0;
      run += v;
      sacc[k] = run;
    }
    int x = run;
#pragma unroll
    for (int off = 1; off < 64; off <<= 1) {
      const int y = __shfl_up(x, off);
      if (lane >= off) x += y;
    }
    if (lane == 63) wtot[wv] = x;
    __syncthreads();
    int woff = 0;
#pragma unroll
    for (int k = 0; k < 16; k++) woff += (k < wv) ? wtot[k] : 0;
    const int thr_excl = (x - run) + woff + carry_s;
#pragma unroll
    for (int k = 0; k < 8; k++)
      if (i0 + k < n) row[i0 + k + 1] = thr_excl + sacc[k];
    __syncthreads();
    if (tid == 1023) carry_s = thr_excl + run;
    __syncthreads();
  }
}

__global__ __launch_bounds__(256) void scatter2_kernel(
    const int* __restrict__ src, const int* __restrict__ dst,
    const int* __restrict__ PH, const int* __restrict__ rowU,
    const int* __restrict__ rowI, int* __restrict__ adjU,
    int* __restrict__ adjI) {
  __shared__ int pos[HSLOTS];
  const int x = blockIdx.x & (NXCD - 1);
  const int s = blockIdx.x >> 3;
  const int uLo = x * U_LOC, iLo = x * I_LOC;
  const int* pre = PH + (size_t)blockIdx.x * HSLOTS;
  for (int i = threadIdx.x; i < U_LOC; i += 256)
    pos[i] = rowU[uLo + i] + pre[i];
  for (int i = threadIdx.x; i < I_LOC; i += 256)
    pos[U_LOC + i] = rowI[iLo + i] + pre[U_LOC + i];
  __syncthreads();
  const int e0 = s * E_SLICE;
  for (int e = e0 + threadIdx.x; e < e0 + E_SLICE; e += 256) {
    const int u  = __builtin_nontemporal_load(&src[e]);
    const int it = __builtin_nontemporal_load(&dst[e]);
    const int ul = u - uLo, il = it - iLo;
    if ((unsigned)ul < (unsigned)U_LOC) {
      const int p = atomicAdd(&pos[ul], 1);
      adjU[p] = it;
    }
    if ((unsigned)il < (unsigned)I_LOC) {
      const int p = atomicAdd(&pos[U_LOC + il], 1);
      adjI[p] = u;
    }
  }
}

// ---------------- aggregations: one wave per segment, lane = channel ----------------
__global__ __launch_bounds__(256) void agg_max_kernel(
    const float* __restrict__ feat, const int* __restrict__ rowptr,
    const int* __restrict__ adj, float* __restrict__ out, int nseg) {
  const int lane = threadIdx.x & 63;
  const int wid  = rfl((int)(threadIdx.x >> 6));
  for (int s = blockIdx.x * 4 + wid; s < nseg; s += gridDim.x * 4) {
    const int beg = rowptr[s], end = rowptr[s + 1];
    float m0 = -INFINITY, m1 = -INFINITY, m2 = -INFINITY, m3 = -INFINITY;
    int j = beg;
    for (; j + 4 <= end; j += 4) {
      const int n0 = adj[j], n1 = adj[j + 1], n2 = adj[j + 2], n3 = adj[j + 3];
      m0 = fmaxf(m0, feat[(size_t)n0 * H + lane]);
      m1 = fmaxf(m1, feat[(size_t)n1 * H + lane]);
      m2 = fmaxf(m2, feat[(size_t)n2 * H + lane]);
      m3 = fmaxf(m3, feat[(size_t)n3 * H + lane]);
    }
    for (; j < end; j++) m0 = fmaxf(m0, feat[(size_t)adj[j] * H + lane]);
    const float m = fmaxf(fmaxf(m0, m1), fmaxf(m2, m3));
    out[(size_t)s * H + lane] = (end > beg) ? m : 0.f;  // empty segment -> 0 (PyG)
  }
}

__global__ __launch_bounds__(256) void agg_mean_kernel(
    const float* __restrict__ feat, const int* __restrict__ rowptr,
    const int* __restrict__ adj, float* __restrict__ out, int nseg) {
  const int lane = threadIdx.x & 63;
  const int wid  = rfl((int)(threadIdx.x >> 6));
  for (int s = blockIdx.x * 4 + wid; s < nseg; s += gridDim.x * 4) {
    const int beg = rowptr[s], end = rowptr[s + 1];
    float a0 = 0.f, a1 = 0.f, a2 = 0.f, a3 = 0.f;
    int j = beg;
    for (; j + 4 <= end; j += 4) {
      const int n0 = adj[j], n1 = adj[j + 1], n2 = adj[j + 2], n3 = adj[j + 3];
      a0 += feat[(size_t)n0 * H + lane];
      a1 += feat[(size_t)n1 * H + lane];
      a2 += feat[(size_t)n2 * H + lane];
      a3 += feat[(size_t)n3 * H + lane];
    }
    for (; j < end; j++) a0 += feat[(size_t)adj[j] * H + lane];
    const float inv = 1.f / (float)((end - beg) > 1 ? (end - beg) : 1);
    out[(size_t)s * H + lane] = ((a0 + a1) + (a2 + a3)) * inv;
  }
}

// ---------------- fused conv: Y = relu(BN(AGG@Wl + bl + XS@Wr)) ----------------
// One row per wave per iteration (single sequential uniform stream), K=128
// weights in VGPRs, 4 split accumulators for ILP, no barriers.
__global__ __launch_bounds__(256) void conv_kernel(
    const float* __restrict__ AGG, const float* __restrict__ XS,
    const float* __restrict__ Wl, const float* __restrict__ bl,
    const float* __restrict__ Wr, const float* __restrict__ gm,
    const float* __restrict__ bt, const float* __restrict__ mu,
    const float* __restrict__ vr, float* __restrict__ Y, int nrows) {
  const int lane = threadIdx.x & 63;
  const int wid  = rfl((int)(threadIdx.x >> 6));
  float wl[64], wr[64];
#pragma unroll
  for (int k = 0; k < 64; k++) wl[k] = Wl[k * 64 + lane];
#pragma unroll
  for (int k = 0; k < 64; k++) wr[k] = Wr[k * 64 + lane];
  const float s = gm[lane] * rsqrtf(vr[lane] + BN_EPS);
  const float C = (bl[lane] - mu[lane]) * s + bt[lane];
  for (int r = blockIdx.x * 4 + wid; r < nrows; r += gridDim.x * 4) {
    const float* a = AGG + (size_t)r * 64;
    const float* x = XS + (size_t)r * 64;
    float c0 = 0.f, c1 = 0.f, c2 = 0.f, c3 = 0.f;
#pragma unroll
    for (int k = 0; k < 64; k += 4) {
      c0 = fmaf(a[k + 0], wl[k + 0], c0);
      c1 = fmaf(a[k + 1], wl[k + 1], c1);
      c2 = fmaf(a[k + 2], wl[k + 2], c2);
      c3 = fmaf(a[k + 3], wl[k + 3], c3);
    }
#pragma unroll
    for (int k = 0; k < 64; k += 4) {
      c0 = fmaf(x[k + 0], wr[k + 0], c0);
      c1 = fmaf(x[k + 1], wr[k + 1], c1);
      c2 = fmaf(x[k + 2], wr[k + 2], c2);
      c3 = fmaf(x[k + 3], wr[k + 3], c3);
    }
    const float acc = (c0 + c1) + (c2 + c3);
    Y[(size_t)r * 64 + lane] = fmaxf(fmaf(acc, s, C), 0.f);
  }
}

// ---------------- head ----------------
__global__ __launch_bounds__(256) void head_kernel(
    const float* __restrict__ ux, const float* __restrict__ ix,
    const int* __restrict__ eliU, const int* __restrict__ eliI,
    const float* __restrict__ W1, const float* __restrict__ b1,
    const float* __restrict__ W2, const float* __restrict__ b2,
    float* __restrict__ out) {
  const int lane = threadIdx.x & 63;
  const int wid  = rfl((int)(threadIdx.x >> 6));
  float w1[128];
#pragma unroll
  for (int k = 0; k < 128; k++) w1[k] = W1[k * 64 + lane];
  const float b1v = b1[lane];
  const float w2a = W2[lane * 4 + 0], w2b = W2[lane * 4 + 1];
  const float w2c = W2[lane * 4 + 2], w2d = W2[lane * 4 + 3];
  const float c0 = b2[0], c1 = b2[1], c2 = b2[2], c3 = b2[3];
  for (int b = blockIdx.x * 4 + wid; b < NB; b += gridDim.x * 4) {
    const int u = eliU[b], it = eliI[b];
    const float* xu = ux + (size_t)u * 64;
    const float* xi = ix + (size_t)it * 64;
    float a0 = b1v, a1 = 0.f, a2 = 0.f, a3 = 0.f;
#pragma unroll
    for (int k = 0; k < 64; k += 4) {
      a0 = fmaf(xu[k + 0], w1[k + 0], a0);
      a1 = fmaf(xu[k + 1], w1[k + 1], a1);
      a2 = fmaf(xu[k + 2], w1[k + 2], a2);
      a3 = fmaf(xu[k + 3], w1[k + 3], a3);
    }
#pragma unroll
    for (int k = 0; k < 64; k += 4) {
      a0 = fmaf(xi[k + 0], w1[64 + k + 0], a0);
      a1 = fmaf(xi[k + 1], w1[64 + k + 1], a1);
      a2 = fmaf(xi[k + 2], w1[64 + k + 2], a2);
      a3 = fmaf(xi[k + 3], w1[64 + k + 3], a3);
    }
    const float h = fmaxf((a0 + a1) + (a2 + a3), 0.f);
    float o0 = h * w2a, o1 = h * w2b, o2 = h * w2c, o3 = h * w2d;
#pragma unroll
    for (int off = 32; off; off >>= 1) {
      o0 += __shfl_down(o0, off);
      o1 += __shfl_down(o1, off);
      o2 += __shfl_down(o2, off);
      o3 += __shfl_down(o3, off);
    }
    if (lane == 0) {
      float4 o = { o0 + c0, o1 + c1, o2 + c2, o3 + c3 };
      *reinterpret_cast<float4*>(out + (size_t)b * 4) = o;
    }
  }
}

// ---------------- launch ----------------
extern "C" void kernel_launch(void* const* d_in, const int* in_sizes, int n_in,
                              void* d_out, int out_size, void* d_ws, size_t ws_size,
                              hipStream_t stream) {
  const float* userF = (const float*)d_in[0];
  const float* itemF = (const float*)d_in[1];
  const int*   src   = (const int*)d_in[2];
  const int*   dst   = src + NE;
  const int*   eliU  = (const int*)d_in[3];
  const int*   eliI  = eliU + NB;
  const float* upW = (const float*)d_in[4],  *upb = (const float*)d_in[5];
  const float* ipW = (const float*)d_in[6],  *ipb = (const float*)d_in[7];
  const float* ulW = (const float*)d_in[8],  *ulb = (const float*)d_in[9];
  const float* urW = (const float*)d_in[10];
  const float* ilW = (const float*)d_in[11], *ilb = (const float*)d_in[12];
  const float* irW = (const float*)d_in[13];
  const float* ug  = (const float*)d_in[14], *ube = (const float*)d_in[15];
  const float* um  = (const float*)d_in[16], *uv  = (const float*)d_in[17];
  const float* ig  = (const float*)d_in[18], *ibe = (const float*)d_in[19];
  const float* im  = (const float*)d_in[20], *iv  = (const float*)d_in[21];
  const float* f1W = (const float*)d_in[22], *f1b = (const float*)d_in[23];
  const float* f2W = (const float*)d_in[24], *f2b = (const float*)d_in[25];
  float* outp = (float*)d_out;

  char* p = (char*)d_ws;
  auto alloc = [&](size_t bytes) {
    char* r = p;
    p += (bytes + 255) & ~(size_t)255;
    return r;
  };
  float* ux0  = (float*)alloc((size_t)N_USERS * H * 4);
  float* ux1  = (float*)alloc((size_t)N_USERS * H * 4);
  float* ix0  = (float*)alloc((size_t)N_ITEMS * H * 4);
  float* ix1  = (float*)alloc((size_t)N_ITEMS * H * 4);
  float* agU  = (float*)alloc((size_t)N_USERS * H * 4);   // 25.6 MB
  float* agI  = (float*)alloc((size_t)N_ITEMS * H * 4);   // 12.8 MB (contiguous after agU)
  int*   rowU = (int*)alloc((size_t)(N_USERS + 1) * 4);
  int*   rowI = (int*)alloc((size_t)(N_ITEMS + 1) * 4);
  int*   cntU = (int*)alloc((size_t)N_USERS * 4);
  int*   cntI = (int*)alloc((size_t)N_ITEMS * 4);
  int*   adjU = (int*)alloc((size_t)NE * 4);
  int*   adjI = (int*)alloc((size_t)NE * 4);
  // PH (512 x 18750 ints = 38.4 MB) aliases agU+agI (dead until agg phase).
  int*   PH   = (int*)agU;

  const int G = 2048, T = 256;
  proj_kernel<256><<<G, T, 0, stream>>>(userF, upW, upb, ux0, N_USERS);
  proj_kernel<128><<<G, T, 0, stream>>>(itemF, ipW, ipb, ix0, N_ITEMS);
  hist2_kernel<<<NBLK_CSR, T, 0, stream>>>(src, dst, PH);
  combine_kernel<<<(NXCD * HSLOTS + 255) / 256, T, 0, stream>>>(PH, cntU, cntI);
  scan_kernel<<<1, 1024, 0, stream>>>(cntU, rowU, N_USERS);
  scan_kernel<<<1, 1024, 0, stream>>>(cntI, rowI, N_ITEMS);
  scatter2_kernel<<<NBLK_CSR, T, 0, stream>>>(src, dst, PH, rowU, rowI, adjU, adjI);

  const float* uin = ux0;
  const float* iin = ix0;
  float* uout = ux1;
  float* iout = ix1;
  for (int l = 0; l < 2; l++) {
    agg_max_kernel<<<G, T, 0, stream>>>(iin, rowU, adjU, agU, N_USERS);
    conv_kernel<<<G, T, 0, stream>>>(agU, uin, ulW + l * 4096, ulb + l * 64,
                                     urW + l * 4096, ug + l * 64, ube + l * 64,
                                     um + l * 64, uv + l * 64, uout, N_USERS);
    agg_mean_kernel<<<G, T, 0, stream>>>(uin, rowI, adjI, agI, N_ITEMS);
    conv_kernel<<<G, T, 0, stream>>>(agI, iin, ilW + l * 4096, ilb + l * 64,
                                     irW + l * 4096, ig + l * 64, ibe + l * 64,
                                     im + l * 64, iv + l * 64, iout, N_ITEMS);
    const float* t;
    t = uin; uin = uout; uout = (float*)t;
    t = iin; iin = iout; iout = (float*)t;
  }
  head_kernel<<<G, T, 0, stream>>>(uin, iin, eliU, eliI, f1W, f1b, f2W, f2b, outp);
}